// Round 10
// baseline (155.667 us; speedup 1.0000x reference)
//
#include <hip/hip_runtime.h>

#define NE 800000
#define NN 50000
#define MAXD 64
#define FILL_BLK (NE / 256)   // 3125 edge-MLP blocks (exact)
#define XC_BLK (NN / 8)       // 6250 repack blocks (exact)
#define PSTR 516              // LDS P row stride in f16 (pad 4 -> conflict-free)

typedef __attribute__((ext_vector_type(4))) unsigned short ushort4v;
typedef __attribute__((ext_vector_type(4))) _Float16 f16x4;
typedef __attribute__((ext_vector_type(4))) float f32x4;

static constexpr float ALPHA      = 0.08838834764831845f;   // 1/sqrt(128)
static constexpr float INV3       = 0.57735026918962576f;   // 1/sqrt(3)
static constexpr float INV_SQRT10 = 0.31622776601683794f;
static constexpr float SILU_NORM  = 1.679177f;
static constexpr float QSCALE     = ALPHA * 0.25f;          // fold 1/sqrt(16)

__device__ __forceinline__ unsigned short f2h_bits(float f) {
  _Float16 h = (_Float16)f;
  unsigned short b;
  __builtin_memcpy(&b, &h, 2);
  return b;
}
__device__ __forceinline__ float h2f_bits(unsigned int b) {
  unsigned short s = (unsigned short)b;
  _Float16 h;
  __builtin_memcpy(&h, &s, 2);
  return (float)h;
}
__device__ __forceinline__ unsigned int packh2(float lo, float hi) {
  return (unsigned int)f2h_bits(lo) | ((unsigned int)f2h_bits(hi) << 16);
}

// ---- fused: edge MLP -> ELL fill (blocks [0, FILL_BLK)) and
//      X f32 -> f16 repack (blocks [FILL_BLK, FILL_BLK+XC_BLK)).
__global__ __launch_bounds__(256) void k_combo(
    const float* __restrict__ X, unsigned short* __restrict__ Xp,
    const float* __restrict__ attr, const float* __restrict__ emb,
    const float* __restrict__ w1, const float* __restrict__ w2,
    const int* __restrict__ esrc, const int* __restrict__ edst,
    int* __restrict__ cur, uint4* __restrict__ ell) {
  __shared__ float lds[2816];  // 11.3 KB, shared by both paths
  if (blockIdx.x < FILL_BLK) {
    // ---- edge MLP + ELL fill; atomic issued EARLY, hidden under MLP ----
    int eb = blockIdx.x * 256;
    int e = eb + threadIdx.x;
    int dst = edst[e];
    int src = esrc[e];
    float4 a = *(const float4*)(attr + (size_t)e * 4);
    int slot = atomicAdd(&cur[dst], 1);

    const float* ebase = emb + (size_t)eb * 10;
#pragma unroll
    for (int j = 0; j < 10; j++)
      lds[j * 256 + threadIdx.x] = ebase[j * 256 + threadIdx.x];
    __syncthreads();
    const float* x = lds + threadIdx.x * 10;
    float r = 0.f;
#pragma unroll
    for (int j = 0; j < 64; j++) {
      float d = 0.f;
#pragma unroll
      for (int k = 0; k < 10; k++) d = fmaf(x[k], w1[k * 64 + j], d);
      d *= INV_SQRT10;
      float h = d * __builtin_amdgcn_rcpf(1.f + __expf(-d)) * SILU_NORM;
      r = fmaf(h, w2[j], r);
    }
    r *= 0.125f * QSCALE;  // fold 1/sqrt(64), alpha, 1/sqrt(16)
    if (slot < MAXD) {
      // single 16B scattered store per edge (one cache line touched)
      ell[(size_t)dst * MAXD + slot] =
          make_uint4((unsigned)src, packh2(r * a.x, r * a.y),
                     packh2(r * a.z, r * a.w), 0u);
    }
  } else {
    // ---- X -> Xp repack: 8 node rows staged via coalesced float4 loads ----
    int n0 = (blockIdx.x - FILL_BLK) * 8;
    const float4* Xs = (const float4*)(X + (size_t)n0 * 256);
    float4* L4 = (float4*)lds;
    L4[threadIdx.x] = Xs[threadIdx.x];
    L4[256 + threadIdx.x] = Xs[256 + threadIdx.x];
    __syncthreads();
    int o = threadIdx.x & 63;
    int nl = threadIdx.x >> 6;
#pragma unroll
    for (int ii = 0; ii < 2; ii++) {
      int n_l = nl + ii * 4;
      const float* row = lds + n_l * 256;
      ushort4v v;
      v[0] = f2h_bits(row[o]);
      v[1] = f2h_bits(row[64 + 3 * o]);
      v[2] = f2h_bits(row[64 + 3 * o + 1]);
      v[3] = f2h_bits(row[64 + 3 * o + 2]);
      *(ushort4v*)(Xp + (size_t)(n0 + n_l) * 256 + o * 4) = v;
    }
  }
}

// ---- raw-feature accumulate for one edge ----
__device__ __forceinline__ void eop(unsigned int q01, unsigned int q23,
                                    ushort4v y, float& u0, float& u1,
                                    float& v0, float& v1, float& v2, float& w0,
                                    float& w1, float& w2) {
  float q0 = h2f_bits(q01), q1 = h2f_bits(q01 >> 16);
  float q2 = h2f_bits(q23), q3 = h2f_bits(q23 >> 16);
  float x0 = h2f_bits(y[0]), xa = h2f_bits(y[1]);
  float xb = h2f_bits(y[2]), xc = h2f_bits(y[3]);
  u0 = fmaf(q0, x0, u0);
  u1 = fmaf(q1, xa, u1);
  u1 = fmaf(q2, xb, u1);
  u1 = fmaf(q3, xc, u1);
  v0 = fmaf(q1, x0, v0);
  v1 = fmaf(q2, x0, v1);
  v2 = fmaf(q3, x0, v2);
  w0 = fmaf(q0, xa, w0);
  w1 = fmaf(q0, xb, w1);
  w2 = fmaf(q0, xc, w2);
}

// ---- fused aggregation + MFMA post-transform ----
// Block = 512 threads = 8 waves, 16 nodes. Phase 1: wave w aggregates nodes
// nb+w and nb+w+8 (2 nodes/wave halves the block-straggler penalty vs 16
// independent waves: wall = max over 8 of 2-node sums). 8-deep gather
// pipeline. Phase 2: wave w computes MFMA pieces w and w+8 of the 16-node
// tile (piece = (j = pi&3, part = pi>>2)).
// v_mfma_f32_16x16x16f16: A row=l&15, k=(l>>4)*4+i; B col=l&15; D col=l&15,
// row=(l>>4)*4+r (validated rounds 6-9).
__global__ __launch_bounds__(512) void k_aggpost(
    const int* __restrict__ cur, const uint4* __restrict__ ell,
    const unsigned short* __restrict__ Xp, const float* __restrict__ W00,
    const float* __restrict__ W11, const float* __restrict__ W01,
    const float* __restrict__ W10, float* __restrict__ out) {
  __shared__ unsigned short Pl[16 * PSTR];  // 16.5 KB
  int w = threadIdx.x >> 6;  // 0..7
  int o = threadIdx.x & 63;
  int nb = blockIdx.x * 16;

  // ---- phase 1: aggregate 2 nodes per wave ----
#pragma unroll
  for (int half = 0; half < 2; half++) {
    int n = nb + w + half * 8;
    int d = cur[n];
    if (d > MAXD) d = MAXD;
    const uint4* base = ell + (size_t)n * MAXD;

    float u0 = 0.f, u1 = 0.f, v0 = 0.f, v1 = 0.f, v2 = 0.f;
    float w0 = 0.f, w1 = 0.f, w2 = 0.f;
    int i = 0;
    for (; i + 8 <= d; i += 8) {
      uint4 rec[8];
      ushort4v y[8];
#pragma unroll
      for (int q = 0; q < 8; q++) rec[q] = base[i + q];
#pragma unroll
      for (int q = 0; q < 8; q++)
        y[q] = *(const ushort4v*)(Xp + ((size_t)rec[q].x << 8) + (o << 2));
#pragma unroll
      for (int q = 0; q < 8; q++)
        eop(rec[q].y, rec[q].z, y[q], u0, u1, v0, v1, v2, w0, w1, w2);
    }
    for (; i + 2 <= d; i += 2) {
      uint4 rec[2];
      ushort4v y[2];
#pragma unroll
      for (int q = 0; q < 2; q++) rec[q] = base[i + q];
#pragma unroll
      for (int q = 0; q < 2; q++)
        y[q] = *(const ushort4v*)(Xp + ((size_t)rec[q].x << 8) + (o << 2));
#pragma unroll
      for (int q = 0; q < 2; q++)
        eop(rec[q].y, rec[q].z, y[q], u0, u1, v0, v1, v2, w0, w1, w2);
    }
    if (i < d) {
      uint4 rec = base[i];
      ushort4v y = *(const ushort4v*)(Xp + ((size_t)rec.x << 8) + (o << 2));
      eop(rec.y, rec.z, y, u0, u1, v0, v1, v2, w0, w1, w2);
    }

    int rb = (w + half * 8) * PSTR;
    Pl[rb + 0 * 64 + o] = f2h_bits(u0);
    Pl[rb + 1 * 64 + o] = f2h_bits(u1 * INV3);
    Pl[rb + 2 * 64 + o] = f2h_bits(v0);
    Pl[rb + 3 * 64 + o] = f2h_bits(v1);
    Pl[rb + 4 * 64 + o] = f2h_bits(v2);
    Pl[rb + 5 * 64 + o] = f2h_bits(w0);
    Pl[rb + 6 * 64 + o] = f2h_bits(w1);
    Pl[rb + 7 * 64 + o] = f2h_bits(w2);
  }
  __syncthreads();

  // ---- phase 2: MFMA post-transform, 2 pieces per wave ----
  int lr = o & 15, lq = o >> 4;
#pragma unroll
  for (int pi = w; pi < 16; pi += 8) {
    int j = pi & 3;      // 16-col block
    int part = pi >> 2;  // 0: out0; 1..3: out1_m
    int col = 16 * j + lr;

    int c0 = (part == 0) ? 0 : 2 + (part - 1);
    int c1 = (part == 0) ? 1 : 5 + (part - 1);
    const float* Wp0 = (part == 0) ? W00 : W01;
    const float* Wp1 = (part == 0) ? W11 : W10;

    f16x4 a0[4], a1[4], b0[4], b1[4];
#pragma unroll
    for (int kq = 0; kq < 4; kq++) {
      int od = kq * 16 + lq * 4;
      ushort4v t0 = *(const ushort4v*)(Pl + lr * PSTR + c0 * 64 + od);
      ushort4v t1 = *(const ushort4v*)(Pl + lr * PSTR + c1 * 64 + od);
      __builtin_memcpy(&a0[kq], &t0, 8);
      __builtin_memcpy(&a1[kq], &t1, 8);
#pragma unroll
      for (int ii = 0; ii < 4; ii++) {
        int row = od + ii;
        b0[kq][ii] = (_Float16)Wp0[row * 64 + col];
        b1[kq][ii] = (_Float16)Wp1[row * 64 + col];
      }
    }

    f32x4 acc = {0.f, 0.f, 0.f, 0.f};
#pragma unroll
    for (int kq = 0; kq < 4; kq++) {
      acc = __builtin_amdgcn_mfma_f32_16x16x16f16(a0[kq], b0[kq], acc, 0, 0, 0);
      acc = __builtin_amdgcn_mfma_f32_16x16x16f16(a1[kq], b1[kq], acc, 0, 0, 0);
    }

    if (part == 0) {
#pragma unroll
      for (int r = 0; r < 4; r++)
        out[(size_t)(nb + lq * 4 + r) * 256 + col] = acc[r];
    } else {
      int m = part - 1;
#pragma unroll
      for (int r = 0; r < 4; r++)
        out[(size_t)(nb + lq * 4 + r) * 256 + 64 + 3 * col + m] = acc[r];
    }
  }
}

extern "C" void kernel_launch(void* const* d_in, const int* in_sizes, int n_in,
                              void* d_out, int out_size, void* d_ws,
                              size_t ws_size, hipStream_t stream) {
  const float* node_in = (const float*)d_in[0];
  const float* edge_attr = (const float*)d_in[1];
  const float* emb = (const float*)d_in[2];
  const float* w00 = (const float*)d_in[3];
  const float* w11 = (const float*)d_in[4];
  const float* w01 = (const float*)d_in[5];
  const float* w10 = (const float*)d_in[6];
  const float* fw1 = (const float*)d_in[7];
  const float* fw2 = (const float*)d_in[8];
  const int* esrc = (const int*)d_in[9];
  const int* edst = (const int*)d_in[10];
  float* out = (float*)d_out;

  char* ws = (char*)d_ws;
  unsigned short* Xp = (unsigned short*)ws; ws += (size_t)NN * 256 * 2;    // 25.6 MB
  uint4* ell = (uint4*)ws;                  ws += (size_t)NN * MAXD * 16;  // 51.2 MB
  int* cur = (int*)ws;                      ws += (size_t)NN * 4;          // 0.2 MB

  (void)hipMemsetAsync(cur, 0, (size_t)NN * 4, stream);
  k_combo<<<FILL_BLK + XC_BLK, 256, 0, stream>>>(
      node_in, Xp, edge_attr, emb, fw1, fw2, esrc, edst, cur, ell);
  k_aggpost<<<NN / 16, 512, 0, stream>>>(cur, ell, Xp, w00, w11, w01, w10,
                                         out);
}